// Round 1
// baseline (527.744 us; speedup 1.0000x reference)
//
#include <hip/hip_runtime.h>
#include <hip/hip_bf16.h>
#include <cstdint>

// SimplifiedMLA: B=32, H=32, S=4096, R=512, D=128, HID=4096
#define Hh   32
#define Dd   128
#define Rr   512
#define Ss   4096
#define Bb   32
#define HID  4096
#define NCH  16      // S-chunks for flash split
#define S_C  256     // s per chunk
#define S_SUB 32     // s per LDS subtile
#define NSUB 8       // subtiles per chunk
#define RK   520     // KV LDS row stride (bf16) : 16B-aligned rows, +4-bank/row shift
#define RQ   520     // Q  LDS row stride
#define RP   40      // P  LDS row stride

typedef __attribute__((ext_vector_type(4)))  float  f32x4;
typedef __attribute__((ext_vector_type(16))) float  f32x16;
typedef __attribute__((ext_vector_type(8)))  __bf16 bf16x8;
typedef __attribute__((ext_vector_type(4)))  __bf16 bf16x4;

// ---------------------------------------------------------------------------
// K1/K6: C_part[kq][32][4096] = A[32][4096] x W[4096][4096]^T   (split-K x4)
// MFMA 32x32x16 bf16. A rows = 32 batches (lane&31), B rows = weight rows
// streamed per-lane straight from global (k-contiguous -> L1-friendly).
// ---------------------------------------------------------------------------
__global__ __launch_bounds__(256) void gemm32_splitk(
    const float* __restrict__ A, const float* __restrict__ W,
    float* __restrict__ Cp) {
  const int fb = blockIdx.x & 63, kq = blockIdx.x >> 6;
  const int t = threadIdx.x, L = t & 63, w = t >> 6;
  const int nt = w & 1, kh = w >> 1;           // 2 feature-halves x 2 k-halves
  const int i0 = fb * 64 + nt * 32;
  const int k0 = kq * 1024 + kh * 512;

  const float* ap = A + (size_t)(L & 31) * HID + k0 + ((L >> 5) * 8);
  const float* bp = W + (size_t)(i0 + (L & 31)) * HID + k0 + ((L >> 5) * 8);

  f32x16 acc = {};
  for (int ks = 0; ks < 32; ++ks) {
    f32x4 a0 = *(const f32x4*)(ap);
    f32x4 a1 = *(const f32x4*)(ap + 4);
    f32x4 b0 = *(const f32x4*)(bp);
    f32x4 b1 = *(const f32x4*)(bp + 4);
    ap += 16; bp += 16;
    bf16x8 af, bfr;
#pragma unroll
    for (int e = 0; e < 4; ++e) {
      af[e]      = (__bf16)a0[e];  af[4 + e]  = (__bf16)a1[e];
      bfr[e]     = (__bf16)b0[e];  bfr[4 + e] = (__bf16)b1[e];
    }
    acc = __builtin_amdgcn_mfma_f32_32x32x16_bf16(af, bfr, acc, 0, 0, 0);
  }

  // cross-wave (k-half) reduce through LDS, then store partial
  __shared__ float red[4][32][33];
#pragma unroll
  for (int p = 0; p < 16; ++p) {
    int row = (p & 3) + 8 * (p >> 2) + 4 * (L >> 5);   // batch
    red[w][row][L & 31] = acc[p];
  }
  __syncthreads();
#pragma unroll
  for (int e = 0; e < 8; ++e) {
    int idx = e * 256 + t;             // 0..2047 : 32 b x 64 feats
    int b = idx >> 6, c = idx & 63;
    int ntc = c >> 5, cc = c & 31;
    float v = red[ntc][b][cc] + red[2 + ntc][b][cc];
    Cp[(size_t)kq * (Bb * HID) + (size_t)b * HID + fb * 64 + c] = v;
  }
}

// ---------------------------------------------------------------------------
// K2: q_abs[b][h][r] = SCALE * sum_d (sum_kq q_part + q_b)[b,h*128+d] * w_kc[h,d,r]
// ---------------------------------------------------------------------------
__global__ __launch_bounds__(256) void absorb_q(
    const float* __restrict__ qpart, const float* __restrict__ qb,
    const float* __restrict__ wkc, __bf16* __restrict__ qabs) {
  const int h = blockIdx.x >> 3, rb = blockIdx.x & 7;
  const int t = threadIdx.x;
  __shared__ float qs[Bb][Dd];
#pragma unroll
  for (int i = 0; i < 16; ++i) {
    int idx = i * 256 + t;            // 0..4095 : 32 b x 128 d
    int b = idx >> 7, d = idx & 127;
    float v = qb[h * Dd + d];
    for (int kq = 0; kq < 4; ++kq)
      v += qpart[(size_t)kq * (Bb * HID) + (size_t)b * HID + h * Dd + d];
    qs[b][d] = v;
  }
  __syncthreads();
  const int r = rb * 64 + (t & 63), bq = t >> 6;
  float acc[8] = {};
  for (int d = 0; d < Dd; ++d) {
    float wv = wkc[((size_t)h * Dd + d) * Rr + r];
#pragma unroll
    for (int q = 0; q < 8; ++q) acc[q] += qs[bq * 8 + q][d] * wv;
  }
  const float sc = 0.088388347648318447f;   // 1/sqrt(128)
#pragma unroll
  for (int q = 0; q < 8; ++q) {
    int b = bq * 8 + q;
    qabs[((size_t)b * Hh + h) * Rr + r] = (__bf16)(acc[q] * sc);
  }
}

// ---------------------------------------------------------------------------
// K3: flash latent attention. One block = (batch, 256-s chunk). 512 threads.
// Per 32-s subtile: VGPR-prefetched KV tile -> LDS (bf16), GEMM1 (16x16x32,
// 8-way m/n/k-half wave split, LDS-summed), online softmax, GEMM2 (32x32x16,
// ctx acc in regs, alpha rescale). Emits unnormalized bf16 partials + (m,l).
// ---------------------------------------------------------------------------
__global__ __launch_bounds__(512, 4) void flash_latent(
    const __bf16* __restrict__ qabs, const float* __restrict__ kv,
    __bf16* __restrict__ Apart, float* __restrict__ mlpart) {
  const int b = blockIdx.x >> 4, ch = blockIdx.x & 15;
  const int t = threadIdx.x, L = t & 63, w = t >> 6;

  __shared__ __bf16 Qs[Hh * RQ];        // 33,280 B
  __shared__ __bf16 KVs[S_SUB * RK];    // 33,280 B
  __shared__ __bf16 Ps[Hh * RP];        //  2,560 B
  __shared__ float  Sc[2][Hh][33];      //  8,448 B
  __shared__ float  m_s[Hh], l_s[Hh], al_s[Hh];

  if (t < Hh) { m_s[t] = -1e30f; l_s[t] = 0.f; }

  const int sl = t >> 4, j = t & 15;    // sl: s-row / head row; j: 16-way slice
  const float* kvbase = kv + ((size_t)b * Ss + ch * S_C) * Rr;

  // prefetch tile 0 into regs (32 fp32/thread)
  f32x4 kvb[8];
  {
    const f32x4* p = (const f32x4*)(kvbase + (size_t)sl * Rr);
#pragma unroll
    for (int i = 0; i < 8; ++i) kvb[i] = p[j + i * 16];
  }
  // stage Q (loop-invariant)
  {
    const __bf16* qp = qabs + ((size_t)b * Hh + sl) * Rr;
#pragma unroll
    for (int i = 0; i < 4; ++i) {
      int r = j * 8 + i * 128;
      *(bf16x8*)&Qs[sl * RQ + r] = *(const bf16x8*)(qp + r);
    }
  }

  f32x16 acc2[2] = {{}, {}};
  const int mt = w & 1, ntq = (w >> 1) & 1, kh = w >> 2;

  for (int it = 0; it < NSUB; ++it) {
    __syncthreads();                          // (a) prev compute done
    // convert + store prefetched tile
#pragma unroll
    for (int i = 0; i < 8; ++i) {
      int r = j * 4 + i * 64;
      bf16x4 v;
      v[0] = (__bf16)kvb[i][0]; v[1] = (__bf16)kvb[i][1];
      v[2] = (__bf16)kvb[i][2]; v[3] = (__bf16)kvb[i][3];
      *(bf16x4*)&KVs[sl * RK + r] = v;
    }
    if (it + 1 < NSUB) {                      // issue next-tile loads (overlap)
      const f32x4* p = (const f32x4*)(kvbase + ((size_t)(it + 1) * S_SUB + sl) * Rr);
#pragma unroll
      for (int i = 0; i < 8; ++i) kvb[i] = p[j + i * 16];
    }
    __syncthreads();                          // (b) KVs ready

    // GEMM1: scores[32h][32s] = Q x KV^T, wave = (mt, ntq, kh)
    f32x4 acc1 = {};
    {
      const __bf16* qrow = &Qs[(mt * 16 + (L & 15)) * RQ + ((L >> 4) * 8)];
      const __bf16* krow = &KVs[(ntq * 16 + (L & 15)) * RK + ((L >> 4) * 8)];
#pragma unroll
      for (int ks = 0; ks < 8; ++ks) {
        int k = (kh * 8 + ks) * 32;
        bf16x8 af = *(const bf16x8*)(qrow + k);
        bf16x8 bf = *(const bf16x8*)(krow + k);
        acc1 = __builtin_amdgcn_mfma_f32_16x16x32_bf16(af, bf, acc1, 0, 0, 0);
      }
    }
#pragma unroll
    for (int p = 0; p < 4; ++p)
      Sc[kh][mt * 16 + (L >> 4) * 4 + p][ntq * 16 + (L & 15)] = acc1[p];
    __syncthreads();                          // (c) scores ready

    // online softmax: 16 threads per head, 2 s-values each
    {
      const int hh = sl;
      float v0 = Sc[0][hh][2 * j] + Sc[1][hh][2 * j];
      float v1 = Sc[0][hh][2 * j + 1] + Sc[1][hh][2 * j + 1];
      float mx = fmaxf(v0, v1);
      for (int m = 1; m < 16; m <<= 1) mx = fmaxf(mx, __shfl_xor(mx, m, 16));
      float m_old = m_s[hh];
      float m_new = fmaxf(m_old, mx);
      float p0 = __expf(v0 - m_new), p1 = __expf(v1 - m_new);
      Ps[hh * RP + 2 * j]     = (__bf16)p0;
      Ps[hh * RP + 2 * j + 1] = (__bf16)p1;
      float sum = p0 + p1;
      for (int m = 1; m < 16; m <<= 1) sum += __shfl_xor(sum, m, 16);
      if (j == 0) {
        float al = __expf(m_old - m_new);
        al_s[hh] = al;
        l_s[hh]  = l_s[hh] * al + sum;
        m_s[hh]  = m_new;
      }
    }
    __syncthreads();                          // (d) P/alpha ready

    // rescale ctx acc, then GEMM2: ctx[32h][r] += P x KV  (wave owns 64 r)
#pragma unroll
    for (int p = 0; p < 16; ++p) {
      float al = al_s[(p & 3) + 8 * (p >> 2) + 4 * (L >> 5)];
      acc2[0][p] *= al; acc2[1][p] *= al;
    }
#pragma unroll
    for (int n2 = 0; n2 < 2; ++n2) {
      const int rbase = w * 64 + n2 * 32 + (L & 31);
#pragma unroll
      for (int ks = 0; ks < 2; ++ks) {
        bf16x8 af = *(const bf16x8*)&Ps[(L & 31) * RP + ks * 16 + (L >> 5) * 8];
        bf16x8 bf;
#pragma unroll
        for (int i = 0; i < 8; ++i)   // strided (known 8-way bank conflict)
          bf[i] = KVs[(ks * 16 + (L >> 5) * 8 + i) * RK + rbase];
        acc2[n2] = __builtin_amdgcn_mfma_f32_32x32x16_bf16(af, bf, acc2[n2], 0, 0, 0);
      }
    }
  }

  // epilogue: unnormalized partials (bf16) + (m, l)
  const size_t base = (size_t)(b * NCH + ch) * Hh;
#pragma unroll
  for (int n2 = 0; n2 < 2; ++n2) {
    int r = w * 64 + n2 * 32 + (L & 31);
#pragma unroll
    for (int p = 0; p < 16; ++p) {
      int hh = (p & 3) + 8 * (p >> 2) + 4 * (L >> 5);
      Apart[(base + hh) * Rr + r] = (__bf16)acc2[n2][p];
    }
  }
  if (t < Hh) {
    mlpart[(base + t) * 2]     = m_s[t];
    mlpart[(base + t) * 2 + 1] = l_s[t];
  }
}

// ---------------------------------------------------------------------------
// K4: flash-decoding combine over 16 chunks -> ctx[b][h][r] fp32
// ---------------------------------------------------------------------------
__global__ __launch_bounds__(256) void combine(
    const __bf16* __restrict__ Apart, const float* __restrict__ mlpart,
    float* __restrict__ ctx) {
  const int b = blockIdx.x >> 5, h = blockIdx.x & 31;
  const int t = threadIdx.x;
  __shared__ float mj[NCH], lj[NCH];
  if (t < NCH) {
    mj[t] = mlpart[(((size_t)b * NCH + t) * Hh + h) * 2];
    lj[t] = mlpart[(((size_t)b * NCH + t) * Hh + h) * 2 + 1];
  }
  __syncthreads();
  float M = -1e30f;
  for (int jj = 0; jj < NCH; ++jj) M = fmaxf(M, mj[jj]);
  float wj[NCH]; float Lsum = 0.f;
  for (int jj = 0; jj < NCH; ++jj) { wj[jj] = __expf(mj[jj] - M); Lsum += lj[jj] * wj[jj]; }
  const float inv = 1.0f / Lsum;
#pragma unroll
  for (int rr = 0; rr < 2; ++rr) {
    int r = t + rr * 256;
    float acc = 0.f;
    for (int jj = 0; jj < NCH; ++jj)
      acc += (float)Apart[(((size_t)b * NCH + jj) * Hh + h) * Rr + r] * wj[jj];
    ctx[((size_t)b * Hh + h) * Rr + r] = acc * inv;
  }
}

// ---------------------------------------------------------------------------
// K5: o1[b][h*128+d] = sum_r ctx[b][h][r] * w_vc[h][r][d]
// ---------------------------------------------------------------------------
__global__ __launch_bounds__(256) void vproj(
    const float* __restrict__ ctx, const float* __restrict__ wvc,
    float* __restrict__ o1) {
  const int h = blockIdx.x >> 2, db = blockIdx.x & 3;
  const int t = threadIdx.x;
  __shared__ float cs[Bb][Rr];   // 64 KB
#pragma unroll
  for (int i = 0; i < 64; ++i) {
    int idx = i * 256 + t;
    int bb2 = idx >> 9, r = idx & 511;
    cs[bb2][r] = ctx[((size_t)bb2 * Hh + h) * Rr + r];
  }
  __syncthreads();
  const int d = db * 32 + (t & 31), bq = t >> 5;
  float acc[4] = {};
  for (int r = 0; r < Rr; ++r) {
    float wv = wvc[((size_t)h * Rr + r) * Dd + d];
#pragma unroll
    for (int q = 0; q < 4; ++q) acc[q] += cs[bq * 4 + q][r] * wv;
  }
#pragma unroll
  for (int q = 0; q < 4; ++q)
    o1[(size_t)(bq * 4 + q) * HID + h * Dd + d] = acc[q];
}

// ---------------------------------------------------------------------------
// K7: out = sum_kq out_part + o_b
// ---------------------------------------------------------------------------
__global__ __launch_bounds__(256) void reduce_bias(
    const float* __restrict__ part, const float* __restrict__ bias,
    float* __restrict__ out) {
  const int idx = blockIdx.x * 256 + threadIdx.x;
  float v = bias[idx & (HID - 1)];
  for (int kq = 0; kq < 4; ++kq) v += part[(size_t)kq * (Bb * HID) + idx];
  out[idx] = v;
}

// ---------------------------------------------------------------------------
extern "C" void kernel_launch(void* const* d_in, const int* in_sizes, int n_in,
                              void* d_out, int out_size, void* d_ws, size_t ws_size,
                              hipStream_t stream) {
  const float* hs  = (const float*)d_in[0];
  const float* kv  = (const float*)d_in[1];
  const float* qw  = (const float*)d_in[2];
  const float* qb  = (const float*)d_in[3];
  const float* wkc = (const float*)d_in[4];
  const float* wvc = (const float*)d_in[5];
  const float* ow  = (const float*)d_in[6];
  const float* ob  = (const float*)d_in[7];
  float* out = (float*)d_out;

  char* ws = (char*)d_ws;
  float*  q_part   = (float*) (ws);                       // 2 MB
  __bf16* q_abs    = (__bf16*)(ws + ((size_t)2  << 20));  // 1 MB
  __bf16* A_part   = (__bf16*)(ws + ((size_t)3  << 20));  // 16 MB
  float*  ml_part  = (float*) (ws + ((size_t)19 << 20));  // 128 KB
  float*  ctx      = (float*) (ws + ((size_t)20 << 20));  // 2 MB
  float*  o1       = (float*) (ws + ((size_t)22 << 20));  // 512 KB
  float*  out_part = (float*) (ws + ((size_t)23 << 20));  // 2 MB

  gemm32_splitk<<<256, 256, 0, stream>>>(hs, qw, q_part);
  absorb_q     <<<256, 256, 0, stream>>>(q_part, qb, wkc, q_abs);
  flash_latent <<<512, 512, 0, stream>>>(q_abs, kv, A_part, ml_part);
  combine      <<<1024, 256, 0, stream>>>(A_part, ml_part, ctx);
  vproj        <<<128, 256, 0, stream>>>(ctx, wvc, o1);
  gemm32_splitk<<<256, 256, 0, stream>>>(o1, ow, out_part);
  reduce_bias  <<<512, 256, 0, stream>>>(out_part, ob, out);
}